// Round 17
// baseline (156.571 us; speedup 1.0000x reference)
//
#include <hip/hip_runtime.h>
#include <stdint.h>

#define B_ 32
#define S_ 8192
#define D_ 128
#define H_ 256

typedef __attribute__((ext_vector_type(4))) float f32x4;
typedef __attribute__((ext_vector_type(16))) float f32x16;
typedef __attribute__((ext_vector_type(8))) short bf16x8;
typedef __attribute__((ext_vector_type(4))) unsigned int u32x4;

__device__ __forceinline__ unsigned short f2bf(float f) {
    union { float f; unsigned int u; } v; v.f = f;
    unsigned int r = v.u + 0x7fffu + ((v.u >> 16) & 1u);
    return (unsigned short)(r >> 16);
}
__device__ __forceinline__ float bf2f(unsigned short u) {
    union { unsigned int u; float f; } v; v.u = ((unsigned int)u) << 16;
    return v.f;
}
__device__ __forceinline__ float silu_f(float v) {
    return v * __builtin_amdgcn_rcpf(1.0f + __expf(-v));
}
__device__ __forceinline__ unsigned int cvtpk(float lo, float hi) {
    unsigned int r;
    asm("v_cvt_pk_bf16_f32 %0, %1, %2" : "=v"(r) : "v"(lo), "v"(hi));
    return r;
}
__device__ __forceinline__ void plswap(unsigned int& a, unsigned int& b) {
    asm("v_permlane32_swap_b32 %0, %1" : "+v"(a), "+v"(b));
}
__device__ __forceinline__ void gl16(const void* g, void* l) {
    __builtin_amdgcn_global_load_lds(
        (const __attribute__((address_space(1))) unsigned int*)g,
        (__attribute__((address_space(3))) unsigned int*)l, 16, 0, 0);
}

// ===== prep: 16KB weight PACKAGES + Wq A-frag image + b1 rearrange =====
__global__ void k_prep(const float* __restrict__ Wq, const float* __restrict__ W1,
                       const float* __restrict__ W2, const float* __restrict__ b1,
                       unsigned short* __restrict__ wq_img,
                       unsigned short* __restrict__ wpkg,
                       float* __restrict__ b1r) {
    __shared__ __align__(16) unsigned short tile[8192];
    int t = threadIdx.x, blk = blockIdx.x;
    if (blk < 128) {                       // W1 [b][d][h] -> pkg W1 part, tile=[h][d]
        int b = blk >> 2, hc = blk & 3;
#pragma unroll
        for (int i = 0; i < 8; i++) {
            int idx = t + i * 256;                 // 2048 f32x4 loads
            int d = idx >> 4, hj = idx & 15;
            f32x4 v = *(const f32x4*)(W1 + ((size_t)(b * D_ + d)) * H_ + hc * 64 + hj * 4);
#pragma unroll
            for (int u = 0; u < 4; u++) tile[(hj * 4 + u) * 128 + d] = f2bf(v[u]);
        }
        __syncthreads();
        char* img = (char*)wpkg + (size_t)b * 131072 + (size_t)hc * 32768;
#pragma unroll
        for (int i = 0; i < 4; i++) {
            int c = t + i * 256;                   // 1024 chunks
            int n = c >> 9, kk = (c >> 6) & 7, l = c & 63;
            u32x4 v = *(const u32x4*)(tile + (n * 32 + (l & 31)) * 128 + kk * 16 + (l >> 5) * 8);
            *(u32x4*)(img + n * 16384 + kk * 1024 + l * 16) = v;
        }
    } else if (blk < 256) {                // W2 [b][h][d] -> pkg W2 part, tile=[d][h]
        int a = blk - 128;
        int b = a >> 2, hc = a & 3;
#pragma unroll
        for (int i = 0; i < 8; i++) {
            int idx = t + i * 256;
            int h = idx >> 5, d4 = idx & 31;
            f32x4 v = *(const f32x4*)(W2 + ((size_t)(b * H_ + hc * 64 + h)) * D_ + d4 * 4);
#pragma unroll
            for (int u = 0; u < 4; u++) tile[(d4 * 4 + u) * 64 + h] = f2bf(v[u]);
        }
        __syncthreads();
        char* img = (char*)wpkg + (size_t)b * 131072 + (size_t)hc * 32768;
#pragma unroll
        for (int i = 0; i < 4; i++) {
            int c = t + i * 256;
            int dn = c >> 8, n = (c >> 7) & 1, kk2 = (c >> 6) & 1, l = c & 63;
            u32x4 v = *(const u32x4*)(tile + (dn * 32 + (l & 31)) * 64 + n * 32 + kk2 * 16 + (l >> 5) * 8);
            *(u32x4*)(img + n * 16384 + 8192 + dn * 2048 + kk2 * 1024 + l * 16) = v;
        }
    } else if (blk < 260) {                // Wq [e][d] -> A-frag image
        int base = (blk - 256) * 512;
#pragma unroll
        for (int i = 0; i < 2; i++) {
            int c = base + i * 256 + t;            // 0..2047
            int n = c >> 9, kk = (c >> 6) & 7, l = c & 63;
            int e = n * 32 + (l & 31), d = kk * 16 + (l >> 5) * 8;
            f32x4 v0 = *(const f32x4*)(Wq + e * 128 + d);
            f32x4 v1 = *(const f32x4*)(Wq + e * 128 + d + 4);
            u32x4 o;
            o[0] = cvtpk(v0[0], v0[1]); o[1] = cvtpk(v0[2], v0[3]);
            o[2] = cvtpk(v1[0], v1[1]); o[3] = cvtpk(v1[2], v1[3]);
            *(u32x4*)((char*)wq_img + (size_t)c * 16) = o;
        }
    } else {                               // b1 rearrange
        int idx = (blk - 260) * 256 + t;   // 8192
        int b = idx >> 8, rem = idx & 255;
        int hc = rem >> 6, n = (rem >> 5) & 1, hi = (rem >> 4) & 1, r = rem & 15;
        int h = hc * 64 + n * 32 + (r & 3) + 8 * (r >> 2) + 4 * hi;
        b1r[idx] = b1[b * H_ + h];
    }
}

// ===== GEMM1 (swapped, v2): q^T = Wq@x^T; Wq frags from LDS, x frags from regs =====
__global__ __launch_bounds__(256, 1) void k_qproj(
        const float* __restrict__ x, const unsigned short* __restrict__ wq_img,
        unsigned short* __restrict__ q_img, float* __restrict__ part) {
    __shared__ __align__(16) char lds[34816];   // 32KB wq image + 2KB ss
    int tid = threadIdx.x;
    int lane = tid & 63, w = tid >> 6;
    int c31 = lane & 31, hi = lane >> 5;
    int blk = blockIdx.x;
    int b = blk >> 6, st = blk & 63;

    // stage Wq A-frag image -> LDS (linear, one-shot)
#pragma unroll
    for (int i = 0; i < 8; i++) {
        int off = tid * 16 + i * 4096;
        gl16((const char*)wq_img + off, lds + off);
    }

    // x B-frags: global -> regs (byte-exact; latency hidden under staging)
    const float* xr = x + ((size_t)b * S_ + (size_t)st * 128 + w * 32 + c31) * D_;
    bf16x8 xf[8];
#pragma unroll
    for (int kk = 0; kk < 8; kk++) {
        f32x4 v0 = *(const f32x4*)(xr + kk * 16 + hi * 8);
        f32x4 v1 = *(const f32x4*)(xr + kk * 16 + hi * 8 + 4);
        union { unsigned int u[4]; bf16x8 v; } o;
        o.u[0] = cvtpk(v0[0], v0[1]); o.u[1] = cvtpk(v0[2], v0[3]);
        o.u[2] = cvtpk(v1[0], v1[1]); o.u[3] = cvtpk(v1[2], v1[3]);
        xf[kk] = o.v;
    }
    __syncthreads();   // wq staged

    size_t grp = (size_t)b * 256 + st * 4 + w;
    char* qo = (char*)q_img + grp * 8192;
    float* ssl = (float*)(lds + 32768 + w * 512);   // 128 floats per wave

#pragma unroll
    for (int n = 0; n < 4; n++) {
        f32x16 acch;
#pragma unroll
        for (int e = 0; e < 16; e++) acch[e] = 0.0f;
#pragma unroll
        for (int kk = 0; kk < 8; kk++) {
            bf16x8 wqf = *(const bf16x8*)(lds + n * 8192 + kk * 1024 + lane * 16);
            acch = __builtin_amdgcn_mfma_f32_32x32x16_bf16(wqf, xf[kk], acch, 0, 0, 0);
        }
        float sv[16];
#pragma unroll
        for (int r = 0; r < 16; r++) sv[r] = silu_f(acch[r]);
        unsigned int P[8];
#pragma unroll
        for (int pp = 0; pp < 8; pp++) P[pp] = cvtpk(sv[2 * pp], sv[2 * pp + 1]);
        plswap(P[0], P[2]); plswap(P[1], P[3]);
        plswap(P[4], P[6]); plswap(P[5], P[7]);
        union { unsigned int u[4]; bf16x8 v; } f0, f1;
        f0.u[0] = P[0]; f0.u[1] = P[1]; f0.u[2] = P[2]; f0.u[3] = P[3];
        f1.u[0] = P[4]; f1.u[1] = P[5]; f1.u[2] = P[6]; f1.u[3] = P[7];
        *(bf16x8*)(qo + (2 * n) * 1024 + lane * 16) = f0.v;
        *(bf16x8*)(qo + (2 * n + 1) * 1024 + lane * 16) = f1.v;
        float ssq[16];
#pragma unroll
        for (int r = 0; r < 16; r++) ssq[r] = sv[r] * sv[r];
#pragma unroll
        for (int r = 0; r < 16; r++) {
            ssq[r] += __shfl_xor(ssq[r], 1, 64);
            ssq[r] += __shfl_xor(ssq[r], 2, 64);
            ssq[r] += __shfl_xor(ssq[r], 4, 64);
            ssq[r] += __shfl_xor(ssq[r], 8, 64);
            ssq[r] += __shfl_xor(ssq[r], 16, 64);
        }
        if ((lane & 31) == 0) {
#pragma unroll
            for (int r = 0; r < 16; r++)
                ssl[n * 32 + (r & 3) + 8 * (r >> 2) + 4 * hi] = ssq[r];
        }
    }
    __syncthreads();
    if (tid < 128) {
        float s = *(const float*)(lds + 32768 + 0 * 512 + tid * 4) +
                  *(const float*)(lds + 32768 + 1 * 512 + tid * 4) +
                  *(const float*)(lds + 32768 + 2 * 512 + tid * 4) +
                  *(const float*)(lds + 32768 + 3 * 512 + tid * 4);
        part[((size_t)b * 64 + st) * 128 + tid] = s;
    }
}

// ==== merged: scale = 1/max(||q_col||,1e-12)  +  scale W1 pkg parts in place ====
__global__ void k_scalew(const float* __restrict__ part, unsigned short* __restrict__ wpkg,
                         float* __restrict__ scale) {
    __shared__ float sc_l[128];
    int blk = blockIdx.x;                   // 128 = b*4 + hc
    int b = blk >> 2;
    int t = threadIdx.x;
    if (t < 128) {
        const float* p = part + (size_t)b * 8192 + t;
        float s = 0.0f;
#pragma unroll 8
        for (int i = 0; i < 64; i++) s += p[i * 128];
        float sc = 1.0f / fmaxf(sqrtf(s), 1e-12f);
        sc_l[t] = sc;
        if ((blk & 3) == 0) scale[b * 128 + t] = sc;   // one writer per b
    }
    __syncthreads();
    char* region = (char*)wpkg + (size_t)b * 131072 + (size_t)(blk & 3) * 32768;
#pragma unroll
    for (int i = 0; i < 4; i++) {
        int c = t + i * 256;                // 0..1023 (both n)
        int n = c >> 9, kk = (c >> 6) & 7, l = c & 63;
        char* addr = region + n * 16384 + kk * 1024 + l * 16;
        int d0 = kk * 16 + (l >> 5) * 8;
        u32x4 v = *(const u32x4*)addr;
        const unsigned short* pv = (const unsigned short*)&v;
        u32x4 o;
#pragma unroll
        for (int j = 0; j < 4; j++)
            o[j] = cvtpk(bf2f(pv[2 * j]) * sc_l[d0 + 2 * j],
                         bf2f(pv[2 * j + 1]) * sc_l[d0 + 2 * j + 1]);
        *(u32x4*)addr = o;
    }
}

// ==== fused MLP + LN + residual: round-9 sync, 64 rows/wave (A/B s-groups),
// ==== launch_bounds(256,1) so the unified-VGPR cap is 256 (no spill) ====
__global__ __launch_bounds__(256, 1) void k_mlp(
        const unsigned short* __restrict__ q_img, const float* __restrict__ scale,
        const unsigned short* __restrict__ wpkg, const float* __restrict__ b1r,
        const float* __restrict__ b2, const float* __restrict__ gamma,
        const float* __restrict__ beta, float* __restrict__ out) {
    __shared__ __align__(16) char lds[33792];   // 2 x 16KB pkg ring + 1KB b1
    int tid = threadIdx.x;
    int lane = tid & 63, w = tid >> 6;          // 4 waves
    int c31 = lane & 31, hi = lane >> 5;
    int blk = blockIdx.x;                       // 1024 blocks
    // XCD swizzle: XCD (blk&7) serves batches 4k..4k+3
    int k = blk & 7, j = blk >> 3;              // j 0..127
    int b = k * 4 + (j >> 5);
    int st2 = j & 31;

    const char* wb = (const char*)wpkg + (size_t)b * 131072;
    size_t g0 = (size_t)b * 256 + st2 * 8 + w * 2;   // two consecutive 32-row groups
    const char* qgA = (const char*)q_img + g0 * 8192;
    const char* qgB = qgA + 8192;

    // ---- prologue: q frags (oldest vmem), b1 -> LDS, pkg0/pkg1 -> ring ----
    bf16x8 qfA[8], qfB[8];
#pragma unroll
    for (int kk = 0; kk < 8; kk++) {
        qfA[kk] = *(const bf16x8*)(qgA + kk * 1024 + lane * 16);
        qfB[kk] = *(const bf16x8*)(qgB + kk * 1024 + lane * 16);
    }

    gl16((const char*)b1r + (size_t)b * 1024 + lane * 16, lds + 32768);

#define STAGEPKG(p, slot) do {                                          \
    _Pragma("unroll")                                                   \
    for (int i_ = 0; i_ < 4; i_++) {                                    \
        int off_ = tid * 16 + i_ * 4096;                                \
        gl16(wb + (p) * 16384 + off_, lds + (slot) * 16384 + off_);     \
    } } while (0)

    STAGEPKG(0, 0);
    STAGEPKG(1, 1);

    f32x16 accoA[4], accoB[4];
#pragma unroll
    for (int dn = 0; dn < 4; dn++)
#pragma unroll
        for (int e = 0; e < 16; e++) { accoA[dn][e] = 0.0f; accoB[dn][e] = 0.0f; }

    const float* b1l = (const float*)(lds + 32768);

#pragma unroll
    for (int p = 0; p < 8; p++) {
        const int hc = p >> 1, n = p & 1, slot = p & 1;
        // counted wait: pkg p arrived, pkg p+1 (4 loads) stays in flight
        if (p == 7) { asm volatile("s_waitcnt vmcnt(0)" ::: "memory"); }
        else        { asm volatile("s_waitcnt vmcnt(4)" ::: "memory"); }
        __builtin_amdgcn_s_barrier();
        __builtin_amdgcn_sched_barrier(0);

        // acch init = b1 (identical for both s-groups: depends on h-row only)
        f32x16 acchA, acchB;
        {
            const float* bp = b1l + (hc * 2 + n) * 32 + hi * 16;
#pragma unroll
            for (int jq = 0; jq < 4; jq++) {
                f32x4 bq = *(const f32x4*)(bp + jq * 4);
#pragma unroll
                for (int e = 0; e < 4; e++) {
                    acchA[jq * 4 + e] = bq[e];
                    acchB[jq * 4 + e] = bq[e];
                }
            }
        }
        const char* s0 = lds + slot * 16384;
        // GEMM2 (swapped): one W1 ds_read feeds 2 MFMAs (independent A/B chains)
        __builtin_amdgcn_s_setprio(1);
#pragma unroll
        for (int kk = 0; kk < 8; kk++) {
            bf16x8 wf = *(const bf16x8*)(s0 + kk * 1024 + lane * 16);
            acchA = __builtin_amdgcn_mfma_f32_32x32x16_bf16(wf, qfA[kk], acchA, 0, 0, 0);
            acchB = __builtin_amdgcn_mfma_f32_32x32x16_bf16(wf, qfB[kk], acchB, 0, 0, 0);
        }
        __builtin_amdgcn_s_setprio(0);
        // silu -> bf16 pairs -> permlane swap -> GEMM3 A-frags (both groups)
        bf16x8 paA0, paA1, paB0, paB1;
        {
            float sv[16];
#pragma unroll
            for (int r = 0; r < 16; r++) sv[r] = silu_f(acchA[r]);
            unsigned int P[8];
#pragma unroll
            for (int pp = 0; pp < 8; pp++) P[pp] = cvtpk(sv[2 * pp], sv[2 * pp + 1]);
            plswap(P[0], P[2]); plswap(P[1], P[3]);
            plswap(P[4], P[6]); plswap(P[5], P[7]);
            union { unsigned int u[4]; bf16x8 v; } f0, f1;
            f0.u[0] = P[0]; f0.u[1] = P[1]; f0.u[2] = P[2]; f0.u[3] = P[3];
            f1.u[0] = P[4]; f1.u[1] = P[5]; f1.u[2] = P[6]; f1.u[3] = P[7];
            paA0 = f0.v; paA1 = f1.v;
        }
        {
            float sv[16];
#pragma unroll
            for (int r = 0; r < 16; r++) sv[r] = silu_f(acchB[r]);
            unsigned int P[8];
#pragma unroll
            for (int pp = 0; pp < 8; pp++) P[pp] = cvtpk(sv[2 * pp], sv[2 * pp + 1]);
            plswap(P[0], P[2]); plswap(P[1], P[3]);
            plswap(P[4], P[6]); plswap(P[5], P[7]);
            union { unsigned int u[4]; bf16x8 v; } f0, f1;
            f0.u[0] = P[0]; f0.u[1] = P[1]; f0.u[2] = P[2]; f0.u[3] = P[3];
            f1.u[0] = P[4]; f1.u[1] = P[5]; f1.u[2] = P[6]; f1.u[3] = P[7];
            paB0 = f0.v; paB1 = f1.v;
        }

        // GEMM3: one W2 ds_read feeds 2 MFMAs; 8 independent acco chains
        __builtin_amdgcn_s_setprio(1);
#pragma unroll
        for (int kk2 = 0; kk2 < 2; kk2++)
#pragma unroll
            for (int dn = 0; dn < 4; dn++) {
                bf16x8 wf2 = *(const bf16x8*)(s0 + 8192 + dn * 2048 + kk2 * 1024 + lane * 16);
                accoA[dn] = __builtin_amdgcn_mfma_f32_32x32x16_bf16(kk2 ? paA1 : paA0, wf2,
                                                                    accoA[dn], 0, 0, 0);
                accoB[dn] = __builtin_amdgcn_mfma_f32_32x32x16_bf16(kk2 ? paB1 : paB0, wf2,
                                                                    accoB[dn], 0, 0, 0);
            }
        __builtin_amdgcn_s_setprio(0);

        // all slot reads done (every ds_read consumed by an MFMA above)
        asm volatile("s_waitcnt lgkmcnt(0)" ::: "memory");
        __builtin_amdgcn_sched_barrier(0);
        __builtin_amdgcn_s_barrier();
        if (p < 6) STAGEPKG(p + 2, slot);   // refill freed slot; stays in flight
    }
#undef STAGEPKG

    // ring free -> per-wave 8KB q transpose scratch, used twice (group A then B)
    __syncthreads();
    char* myq = (char*)lds + w * 8192;

    // epilogue params (same for both groups: d-indexed)
    float scv[4], gv[4], bev[4], b2v[4];
#pragma unroll
    for (int dn = 0; dn < 4; dn++) {
        int d = dn * 32 + c31;
        scv[dn] = scale[b * 128 + d];
        gv[dn]  = gamma[b * 128 + d];
        bev[dn] = beta[b * 128 + d];
        b2v[dn] = b2[b * 128 + d];
    }

#define EPILOG(QF, ACCO, GRP) do {                                              \
    _Pragma("unroll")                                                           \
    for (int kk = 0; kk < 8; kk++)                                              \
        *(bf16x8*)(myq + c31 * 256 + ((kk * 32 + hi * 16) ^ ((c31 & 7) << 4))) = QF[kk]; \
    float* og = out + (GRP) * 32 * 128;                                         \
    _Pragma("unroll")                                                           \
    for (int r = 0; r < 16; r++) {                                              \
        float v0 = ACCO[0][r] + b2v[0], v1 = ACCO[1][r] + b2v[1];               \
        float v2 = ACCO[2][r] + b2v[2], v3 = ACCO[3][r] + b2v[3];               \
        float s1 = (v0 + v1) + (v2 + v3);                                       \
        float s2 = (v0 * v0 + v1 * v1) + (v2 * v2 + v3 * v3);                   \
        s1 += __shfl_xor(s1, 1, 64);   s2 += __shfl_xor(s2, 1, 64);             \
        s1 += __shfl_xor(s1, 2, 64);   s2 += __shfl_xor(s2, 2, 64);             \
        s1 += __shfl_xor(s1, 4, 64);   s2 += __shfl_xor(s2, 4, 64);             \
        s1 += __shfl_xor(s1, 8, 64);   s2 += __shfl_xor(s2, 8, 64);             \
        s1 += __shfl_xor(s1, 16, 64);  s2 += __shfl_xor(s2, 16, 64);            \
        float mu = s1 * (1.0f / 128.0f);                                        \
        float var = s2 * (1.0f / 128.0f) - mu * mu;                             \
        float rstd = rsqrtf(var + 1e-5f);                                       \
        int srow0 = (r & 3) + 8 * (r >> 2);                                     \
        int row = srow0 + 4 * hi;                                               \
        float vv[4] = {v0, v1, v2, v3};                                         \
        _Pragma("unroll")                                                       \
        for (int dn = 0; dn < 4; dn++) {                                        \
            float qv = bf2f(*(const unsigned short*)(myq + row * 256 +          \
                        ((dn * 64 + c31 * 2) ^ ((row & 7) << 4)))) * scv[dn];   \
            float o = (vv[dn] - mu) * rstd * gv[dn] + bev[dn] + qv;             \
            og[(size_t)row * 128 + dn * 32 + c31] = o;                          \
        }                                                                       \
    } } while (0)

    EPILOG(qfA, accoA, g0);
    EPILOG(qfB, accoB, (g0 + 1));
#undef EPILOG
}

extern "C" void kernel_launch(void* const* d_in, const int* in_sizes, int n_in,
                              void* d_out, int out_size, void* d_ws, size_t ws_size,
                              hipStream_t stream) {
    (void)in_sizes; (void)n_in; (void)out_size; (void)ws_size;
    const float* x     = (const float*)d_in[0];
    const float* Wq    = (const float*)d_in[1];
    const float* W1    = (const float*)d_in[2];
    const float* b1    = (const float*)d_in[3];
    const float* W2    = (const float*)d_in[4];
    const float* b2    = (const float*)d_in[5];
    const float* gamma = (const float*)d_in[6];
    const float* beta  = (const float*)d_in[7];
    float* out = (float*)d_out;

    char* ws = (char*)d_ws;
    unsigned short* wq_img = (unsigned short*)(ws);                    // 32KB frag image
    unsigned short* wpkg   = (unsigned short*)(ws + 32768);            // 4MB pkg images
    float* part            = (float*)(ws + 4227072);                   // 1MB
    float* scale           = (float*)(ws + 5275648);                   // 16KB
    float* b1r             = (float*)(ws + 5292032);                   // 32KB
    unsigned short* q_img  = (unsigned short*)(ws + 5324800);          // 64MB frag-order q

    hipLaunchKernelGGL(k_prep, dim3(292), dim3(256), 0, stream, Wq, W1, W2, b1, wq_img, wpkg, b1r);
    hipLaunchKernelGGL(k_qproj, dim3(2048), dim3(256), 0, stream, x, wq_img, q_img, part);
    hipLaunchKernelGGL(k_scalew, dim3(128), dim3(256), 0, stream, part, wpkg, scale);
    hipLaunchKernelGGL(k_mlp, dim3(1024), dim3(256), 0, stream,
                       q_img, scale, wpkg, b1r, b2, gamma, beta, out);
}

// Round 18
// 126.402 us; speedup vs baseline: 1.2387x; 1.2387x over previous
//
#include <hip/hip_runtime.h>
#include <stdint.h>

#define B_ 32
#define S_ 8192
#define D_ 128
#define H_ 256

typedef __attribute__((ext_vector_type(4))) float f32x4;
typedef __attribute__((ext_vector_type(16))) float f32x16;
typedef __attribute__((ext_vector_type(8))) short bf16x8;
typedef __attribute__((ext_vector_type(4))) unsigned int u32x4;

__device__ __forceinline__ unsigned short f2bf(float f) {
    union { float f; unsigned int u; } v; v.f = f;
    unsigned int r = v.u + 0x7fffu + ((v.u >> 16) & 1u);
    return (unsigned short)(r >> 16);
}
__device__ __forceinline__ float bf2f(unsigned short u) {
    union { unsigned int u; float f; } v; v.u = ((unsigned int)u) << 16;
    return v.f;
}
__device__ __forceinline__ float silu_f(float v) {
    return v * __builtin_amdgcn_rcpf(1.0f + __expf(-v));
}
__device__ __forceinline__ unsigned int cvtpk(float lo, float hi) {
    unsigned int r;
    asm("v_cvt_pk_bf16_f32 %0, %1, %2" : "=v"(r) : "v"(lo), "v"(hi));
    return r;
}
__device__ __forceinline__ void plswap(unsigned int& a, unsigned int& b) {
    asm("v_permlane32_swap_b32 %0, %1" : "+v"(a), "+v"(b));
}
__device__ __forceinline__ void gl16(const void* g, void* l) {
    __builtin_amdgcn_global_load_lds(
        (const __attribute__((address_space(1))) unsigned int*)g,
        (__attribute__((address_space(3))) unsigned int*)l, 16, 0, 0);
}

// ===== prep: 16KB weight PACKAGES + Wq A-frag image + b1 rearrange =====
// pkg base = b*131072 + hc*32768 + n*16384
//   [0,8192):   W1 frags  kk*1024 + l*16   (h-rows n*32+(l&31), d = kk*16+(l>>5)*8)
//   [8192,16K): W2 frags  dn*2048 + kk2*1024 + l*16
// wq_img chunk c (c = n*512 + kk*64 + l): Wq[e=n*32+(l&31)][d=kk*16+(l>>5)*8 ..+7]
__global__ void k_prep(const float* __restrict__ Wq, const float* __restrict__ W1,
                       const float* __restrict__ W2, const float* __restrict__ b1,
                       unsigned short* __restrict__ wq_img,
                       unsigned short* __restrict__ wpkg,
                       float* __restrict__ b1r) {
    __shared__ __align__(16) unsigned short tile[8192];
    int t = threadIdx.x, blk = blockIdx.x;
    if (blk < 128) {                       // W1 [b][d][h] -> pkg W1 part, tile=[h][d]
        int b = blk >> 2, hc = blk & 3;
#pragma unroll
        for (int i = 0; i < 8; i++) {
            int idx = t + i * 256;                 // 2048 f32x4 loads
            int d = idx >> 4, hj = idx & 15;
            f32x4 v = *(const f32x4*)(W1 + ((size_t)(b * D_ + d)) * H_ + hc * 64 + hj * 4);
#pragma unroll
            for (int u = 0; u < 4; u++) tile[(hj * 4 + u) * 128 + d] = f2bf(v[u]);
        }
        __syncthreads();
        char* img = (char*)wpkg + (size_t)b * 131072 + (size_t)hc * 32768;
#pragma unroll
        for (int i = 0; i < 4; i++) {
            int c = t + i * 256;                   // 1024 chunks
            int n = c >> 9, kk = (c >> 6) & 7, l = c & 63;
            u32x4 v = *(const u32x4*)(tile + (n * 32 + (l & 31)) * 128 + kk * 16 + (l >> 5) * 8);
            *(u32x4*)(img + n * 16384 + kk * 1024 + l * 16) = v;
        }
    } else if (blk < 256) {                // W2 [b][h][d] -> pkg W2 part, tile=[d][h]
        int a = blk - 128;
        int b = a >> 2, hc = a & 3;
#pragma unroll
        for (int i = 0; i < 8; i++) {
            int idx = t + i * 256;
            int h = idx >> 5, d4 = idx & 31;
            f32x4 v = *(const f32x4*)(W2 + ((size_t)(b * H_ + hc * 64 + h)) * D_ + d4 * 4);
#pragma unroll
            for (int u = 0; u < 4; u++) tile[(d4 * 4 + u) * 64 + h] = f2bf(v[u]);
        }
        __syncthreads();
        char* img = (char*)wpkg + (size_t)b * 131072 + (size_t)hc * 32768;
#pragma unroll
        for (int i = 0; i < 4; i++) {
            int c = t + i * 256;
            int dn = c >> 8, n = (c >> 7) & 1, kk2 = (c >> 6) & 1, l = c & 63;
            u32x4 v = *(const u32x4*)(tile + (dn * 32 + (l & 31)) * 64 + n * 32 + kk2 * 16 + (l >> 5) * 8);
            *(u32x4*)(img + n * 16384 + 8192 + dn * 2048 + kk2 * 1024 + l * 16) = v;
        }
    } else if (blk < 260) {                // Wq [e][d] -> A-frag image
        int base = (blk - 256) * 512;
#pragma unroll
        for (int i = 0; i < 2; i++) {
            int c = base + i * 256 + t;            // 0..2047
            int n = c >> 9, kk = (c >> 6) & 7, l = c & 63;
            int e = n * 32 + (l & 31), d = kk * 16 + (l >> 5) * 8;
            f32x4 v0 = *(const f32x4*)(Wq + e * 128 + d);
            f32x4 v1 = *(const f32x4*)(Wq + e * 128 + d + 4);
            u32x4 o;
            o[0] = cvtpk(v0[0], v0[1]); o[1] = cvtpk(v0[2], v0[3]);
            o[2] = cvtpk(v1[0], v1[1]); o[3] = cvtpk(v1[2], v1[3]);
            *(u32x4*)((char*)wq_img + (size_t)c * 16) = o;
        }
    } else {                               // b1 rearrange
        int idx = (blk - 260) * 256 + t;   // 8192
        int b = idx >> 8, rem = idx & 255;
        int hc = rem >> 6, n = (rem >> 5) & 1, hi = (rem >> 4) & 1, r = rem & 15;
        int h = hc * 64 + n * 32 + (r & 3) + 8 * (r >> 2) + 4 * hi;
        b1r[idx] = b1[b * H_ + h];
    }
}

// ===== GEMM1 (swapped, v2): q^T = Wq@x^T; Wq frags from LDS, x frags from regs =====
__global__ __launch_bounds__(256, 1) void k_qproj(
        const float* __restrict__ x, const unsigned short* __restrict__ wq_img,
        unsigned short* __restrict__ q_img, float* __restrict__ part) {
    __shared__ __align__(16) char lds[34816];   // 32KB wq image + 2KB ss
    int tid = threadIdx.x;
    int lane = tid & 63, w = tid >> 6;
    int c31 = lane & 31, hi = lane >> 5;
    int blk = blockIdx.x;
    int b = blk >> 6, st = blk & 63;

    // stage Wq A-frag image -> LDS (linear, one-shot)
#pragma unroll
    for (int i = 0; i < 8; i++) {
        int off = tid * 16 + i * 4096;
        gl16((const char*)wq_img + off, lds + off);
    }

    // x B-frags: global -> regs (byte-exact; latency hidden under staging)
    const float* xr = x + ((size_t)b * S_ + (size_t)st * 128 + w * 32 + c31) * D_;
    bf16x8 xf[8];
#pragma unroll
    for (int kk = 0; kk < 8; kk++) {
        f32x4 v0 = *(const f32x4*)(xr + kk * 16 + hi * 8);
        f32x4 v1 = *(const f32x4*)(xr + kk * 16 + hi * 8 + 4);
        union { unsigned int u[4]; bf16x8 v; } o;
        o.u[0] = cvtpk(v0[0], v0[1]); o.u[1] = cvtpk(v0[2], v0[3]);
        o.u[2] = cvtpk(v1[0], v1[1]); o.u[3] = cvtpk(v1[2], v1[3]);
        xf[kk] = o.v;
    }
    __syncthreads();   // wq staged

    size_t grp = (size_t)b * 256 + st * 4 + w;
    char* qo = (char*)q_img + grp * 8192;
    float* ssl = (float*)(lds + 32768 + w * 512);   // 128 floats per wave

#pragma unroll
    for (int n = 0; n < 4; n++) {
        f32x16 acch;
#pragma unroll
        for (int e = 0; e < 16; e++) acch[e] = 0.0f;
#pragma unroll
        for (int kk = 0; kk < 8; kk++) {
            bf16x8 wqf = *(const bf16x8*)(lds + n * 8192 + kk * 1024 + lane * 16);
            acch = __builtin_amdgcn_mfma_f32_32x32x16_bf16(wqf, xf[kk], acch, 0, 0, 0);
        }
        float sv[16];
#pragma unroll
        for (int r = 0; r < 16; r++) sv[r] = silu_f(acch[r]);
        unsigned int P[8];
#pragma unroll
        for (int pp = 0; pp < 8; pp++) P[pp] = cvtpk(sv[2 * pp], sv[2 * pp + 1]);
        plswap(P[0], P[2]); plswap(P[1], P[3]);
        plswap(P[4], P[6]); plswap(P[5], P[7]);
        union { unsigned int u[4]; bf16x8 v; } f0, f1;
        f0.u[0] = P[0]; f0.u[1] = P[1]; f0.u[2] = P[2]; f0.u[3] = P[3];
        f1.u[0] = P[4]; f1.u[1] = P[5]; f1.u[2] = P[6]; f1.u[3] = P[7];
        *(bf16x8*)(qo + (2 * n) * 1024 + lane * 16) = f0.v;
        *(bf16x8*)(qo + (2 * n + 1) * 1024 + lane * 16) = f1.v;
        float ssq[16];
#pragma unroll
        for (int r = 0; r < 16; r++) ssq[r] = sv[r] * sv[r];
#pragma unroll
        for (int r = 0; r < 16; r++) {
            ssq[r] += __shfl_xor(ssq[r], 1, 64);
            ssq[r] += __shfl_xor(ssq[r], 2, 64);
            ssq[r] += __shfl_xor(ssq[r], 4, 64);
            ssq[r] += __shfl_xor(ssq[r], 8, 64);
            ssq[r] += __shfl_xor(ssq[r], 16, 64);
        }
        if ((lane & 31) == 0) {
#pragma unroll
            for (int r = 0; r < 16; r++)
                ssl[n * 32 + (r & 3) + 8 * (r >> 2) + 4 * hi] = ssq[r];
        }
    }
    __syncthreads();
    if (tid < 128) {
        float s = *(const float*)(lds + 32768 + 0 * 512 + tid * 4) +
                  *(const float*)(lds + 32768 + 1 * 512 + tid * 4) +
                  *(const float*)(lds + 32768 + 2 * 512 + tid * 4) +
                  *(const float*)(lds + 32768 + 3 * 512 + tid * 4);
        part[((size_t)b * 64 + st) * 128 + tid] = s;
    }
}

// ==== merged: scale = 1/max(||q_col||,1e-12)  +  scale W1 pkg parts in place ====
__global__ void k_scalew(const float* __restrict__ part, unsigned short* __restrict__ wpkg,
                         float* __restrict__ scale) {
    __shared__ float sc_l[128];
    int blk = blockIdx.x;                   // 128 = b*4 + hc
    int b = blk >> 2;
    int t = threadIdx.x;
    if (t < 128) {
        const float* p = part + (size_t)b * 8192 + t;
        float s = 0.0f;
#pragma unroll 8
        for (int i = 0; i < 64; i++) s += p[i * 128];
        float sc = 1.0f / fmaxf(sqrtf(s), 1e-12f);
        sc_l[t] = sc;
        if ((blk & 3) == 0) scale[b * 128 + t] = sc;   // one writer per b
    }
    __syncthreads();
    char* region = (char*)wpkg + (size_t)b * 131072 + (size_t)(blk & 3) * 32768;
#pragma unroll
    for (int i = 0; i < 4; i++) {
        int c = t + i * 256;                // 0..1023 (both n)
        int n = c >> 9, kk = (c >> 6) & 7, l = c & 63;
        char* addr = region + n * 16384 + kk * 1024 + l * 16;
        int d0 = kk * 16 + (l >> 5) * 8;
        u32x4 v = *(const u32x4*)addr;
        const unsigned short* pv = (const unsigned short*)&v;
        u32x4 o;
#pragma unroll
        for (int j = 0; j < 4; j++)
            o[j] = cvtpk(bf2f(pv[2 * j]) * sc_l[d0 + 2 * j],
                         bf2f(pv[2 * j + 1]) * sc_l[d0 + 2 * j + 1]);
        *(u32x4*)addr = o;
    }
}

// ==== fused MLP + LN + residual: ROUND-9 structure + T5 setprio on MFMA clusters ====
__global__ __launch_bounds__(256, 2) void k_mlp(
        const unsigned short* __restrict__ q_img, const float* __restrict__ scale,
        const unsigned short* __restrict__ wpkg, const float* __restrict__ b1r,
        const float* __restrict__ b2, const float* __restrict__ gamma,
        const float* __restrict__ beta, float* __restrict__ out) {
    __shared__ __align__(16) char lds[33792];   // 2 x 16KB pkg ring + 1KB b1
    int tid = threadIdx.x;
    int lane = tid & 63, w = tid >> 6;          // 4 waves
    int c31 = lane & 31, hi = lane >> 5;
    int blk = blockIdx.x;
    // XCD swizzle: XCD (blk&7) serves batches 4k..4k+3
    int k = blk & 7, j = blk >> 3;
    int b = k * 4 + (j >> 6);
    int st = j & 63;

    const char* wb = (const char*)wpkg + (size_t)b * 131072;
    size_t grp = (size_t)b * 256 + st * 4 + w;
    const char* qg = (const char*)q_img + grp * 8192;

    // ---- prologue: q frags first (oldest vmem), then b1 -> LDS, then pkg0/pkg1 ----
    bf16x8 qf[8];
#pragma unroll
    for (int kk = 0; kk < 8; kk++)
        qf[kk] = *(const bf16x8*)(qg + kk * 1024 + lane * 16);

    gl16((const char*)b1r + (size_t)b * 1024 + lane * 16, lds + 32768);

#define STAGEPKG(p, slot) do {                                          \
    _Pragma("unroll")                                                   \
    for (int i_ = 0; i_ < 4; i_++) {                                    \
        int off_ = tid * 16 + i_ * 4096;                                \
        gl16(wb + (p) * 16384 + off_, lds + (slot) * 16384 + off_);     \
    } } while (0)

    STAGEPKG(0, 0);
    STAGEPKG(1, 1);

    f32x16 acco[4];
#pragma unroll
    for (int dn = 0; dn < 4; dn++)
#pragma unroll
        for (int e = 0; e < 16; e++) acco[dn][e] = 0.0f;

    const float* b1l = (const float*)(lds + 32768);

#pragma unroll
    for (int p = 0; p < 8; p++) {
        const int hc = p >> 1, n = p & 1, slot = p & 1;
        // counted wait: pkg p arrived, pkg p+1 (4 loads) stays in flight
        if (p == 7) { asm volatile("s_waitcnt vmcnt(0)" ::: "memory"); }
        else        { asm volatile("s_waitcnt vmcnt(4)" ::: "memory"); }
        __builtin_amdgcn_s_barrier();
        __builtin_amdgcn_sched_barrier(0);

        // acch init = b1 (from LDS, lgkm-counted -> no vmcnt pollution)
        f32x16 acch;
        {
            const float* bp = b1l + (hc * 2 + n) * 32 + hi * 16;
#pragma unroll
            for (int jq = 0; jq < 4; jq++) {
                f32x4 bq = *(const f32x4*)(bp + jq * 4);
#pragma unroll
                for (int e = 0; e < 4; e++) acch[jq * 4 + e] = bq[e];
            }
        }
        const char* s0 = lds + slot * 16384;
        // GEMM2 (swapped): D = h^T   [T5: boost MFMA wave priority]
        __builtin_amdgcn_s_setprio(1);
#pragma unroll
        for (int kk = 0; kk < 8; kk++) {
            bf16x8 wf = *(const bf16x8*)(s0 + kk * 1024 + lane * 16);
            acch = __builtin_amdgcn_mfma_f32_32x32x16_bf16(wf, qf[kk], acch, 0, 0, 0);
        }
        __builtin_amdgcn_s_setprio(0);
        // silu -> bf16 pairs -> permlane swap -> GEMM3 A-frags (in regs)
        float sv[16];
#pragma unroll
        for (int r = 0; r < 16; r++) sv[r] = silu_f(acch[r]);
        unsigned int P[8];
#pragma unroll
        for (int pp = 0; pp < 8; pp++) P[pp] = cvtpk(sv[2 * pp], sv[2 * pp + 1]);
        plswap(P[0], P[2]); plswap(P[1], P[3]);
        plswap(P[4], P[6]); plswap(P[5], P[7]);
        union { unsigned int u[4]; bf16x8 v; } f0, f1;
        f0.u[0] = P[0]; f0.u[1] = P[1]; f0.u[2] = P[2]; f0.u[3] = P[3];
        f1.u[0] = P[4]; f1.u[1] = P[5]; f1.u[2] = P[6]; f1.u[3] = P[7];
        bf16x8 pa0 = f0.v, pa1 = f1.v;
        // GEMM3: acco[dn] += h_n @ W2 part   [T5]
        __builtin_amdgcn_s_setprio(1);
#pragma unroll
        for (int kk2 = 0; kk2 < 2; kk2++)
#pragma unroll
            for (int dn = 0; dn < 4; dn++) {
                bf16x8 wf2 = *(const bf16x8*)(s0 + 8192 + dn * 2048 + kk2 * 1024 + lane * 16);
                acco[dn] = __builtin_amdgcn_mfma_f32_32x32x16_bf16(kk2 ? pa1 : pa0, wf2,
                                                                   acco[dn], 0, 0, 0);
            }
        __builtin_amdgcn_s_setprio(0);

        // all slot reads done (every ds_read consumed by an MFMA above)
        asm volatile("s_waitcnt lgkmcnt(0)" ::: "memory");
        __builtin_amdgcn_sched_barrier(0);
        __builtin_amdgcn_s_barrier();
        if (p < 6) STAGEPKG(p + 2, slot);   // refill freed slot; stays in flight
    }
#undef STAGEPKG

    // ring free -> reuse as per-wave q transpose scratch
    __syncthreads();
    char* myq = (char*)lds + w * 8192;    // 8KB per wave, wave-private
#pragma unroll
    for (int kk = 0; kk < 8; kk++)
        *(bf16x8*)(myq + c31 * 256 + ((kk * 32 + hi * 16) ^ ((c31 & 7) << 4))) = qf[kk];

    // epilogue params (loaded late to keep loop register pressure low)
    float scv[4], gv[4], bev[4], b2v[4];
#pragma unroll
    for (int dn = 0; dn < 4; dn++) {
        int d = dn * 32 + c31;
        scv[dn] = scale[b * 128 + d];
        gv[dn]  = gamma[b * 128 + d];
        bev[dn] = beta[b * 128 + d];
        b2v[dn] = b2[b * 128 + d];
    }

    // epilogue: LayerNorm over D + residual q*scale (q from wave-private LDS)
    float* og = out + grp * 32 * 128;
#pragma unroll
    for (int r = 0; r < 16; r++) {
        float v0 = acco[0][r] + b2v[0], v1 = acco[1][r] + b2v[1];
        float v2 = acco[2][r] + b2v[2], v3 = acco[3][r] + b2v[3];
        float s1 = (v0 + v1) + (v2 + v3);
        float s2 = (v0 * v0 + v1 * v1) + (v2 * v2 + v3 * v3);
        s1 += __shfl_xor(s1, 1, 64);   s2 += __shfl_xor(s2, 1, 64);
        s1 += __shfl_xor(s1, 2, 64);   s2 += __shfl_xor(s2, 2, 64);
        s1 += __shfl_xor(s1, 4, 64);   s2 += __shfl_xor(s2, 4, 64);
        s1 += __shfl_xor(s1, 8, 64);   s2 += __shfl_xor(s2, 8, 64);
        s1 += __shfl_xor(s1, 16, 64);  s2 += __shfl_xor(s2, 16, 64);
        float mu = s1 * (1.0f / 128.0f);
        float var = s2 * (1.0f / 128.0f) - mu * mu;
        float rstd = rsqrtf(var + 1e-5f);
        int srow0 = (r & 3) + 8 * (r >> 2);
        int row = srow0 + 4 * hi;
        float vv[4] = {v0, v1, v2, v3};
#pragma unroll
        for (int dn = 0; dn < 4; dn++) {
            float qv = bf2f(*(const unsigned short*)(myq + row * 256 +
                        ((dn * 64 + c31 * 2) ^ ((row & 7) << 4)))) * scv[dn];
            float o = (vv[dn] - mu) * rstd * gv[dn] + bev[dn] + qv;
            og[(size_t)row * 128 + dn * 32 + c31] = o;
        }
    }
}

extern "C" void kernel_launch(void* const* d_in, const int* in_sizes, int n_in,
                              void* d_out, int out_size, void* d_ws, size_t ws_size,
                              hipStream_t stream) {
    (void)in_sizes; (void)n_in; (void)out_size; (void)ws_size;
    const float* x     = (const float*)d_in[0];
    const float* Wq    = (const float*)d_in[1];
    const float* W1    = (const float*)d_in[2];
    const float* b1    = (const float*)d_in[3];
    const float* W2    = (const float*)d_in[4];
    const float* b2    = (const float*)d_in[5];
    const float* gamma = (const float*)d_in[6];
    const float* beta  = (const float*)d_in[7];
    float* out = (float*)d_out;

    char* ws = (char*)d_ws;
    unsigned short* wq_img = (unsigned short*)(ws);                    // 32KB frag image
    unsigned short* wpkg   = (unsigned short*)(ws + 32768);            // 4MB pkg images
    float* part            = (float*)(ws + 4227072);                   // 1MB
    float* scale           = (float*)(ws + 5275648);                   // 16KB
    float* b1r             = (float*)(ws + 5292032);                   // 32KB
    unsigned short* q_img  = (unsigned short*)(ws + 5324800);          // 64MB frag-order q

    hipLaunchKernelGGL(k_prep, dim3(292), dim3(256), 0, stream, Wq, W1, W2, b1, wq_img, wpkg, b1r);
    hipLaunchKernelGGL(k_qproj, dim3(2048), dim3(256), 0, stream, x, wq_img, q_img, part);
    hipLaunchKernelGGL(k_scalew, dim3(128), dim3(256), 0, stream, part, wpkg, scale);
    hipLaunchKernelGGL(k_mlp, dim3(2048), dim3(256), 0, stream,
                       q_img, scale, wpkg, b1r, b2, gamma, beta, out);
}